// Round 1
// baseline (616.167 us; speedup 1.0000x reference)
//
#include <hip/hip_runtime.h>
#include <math.h>

#define NA   21504   // 128^2 + 64^2 + 32^2
#define NA0  16384
#define NA01 20480
#define NG   100
#define NB   16
#define NC   10      // N_CAND

__device__ __forceinline__ float softplusf(float x) {
    // jax.nn.softplus == logaddexp(x,0) == max(x,0) + log1p(exp(-|x|))
    return fmaxf(x, 0.f) + log1pf(expf(-fabsf(x)));
}

__device__ __forceinline__ void anchor_xy(int a, float& xc, float& yc, float& s, int& x, int& y) {
    if (a < NA0)       { x = a & 127;            y = a >> 7;          s = 8.f;  }
    else if (a < NA01) { int i = a - NA0;  x = i & 63; y = i >> 6;    s = 16.f; }
    else               { int i = a - NA01; x = i & 31; y = i >> 5;    s = 32.f; }
    xc = ((float)x + 0.5f) * s;
    yc = ((float)y + 0.5f) * s;
}

// ---------------- init scratch ----------------
__global__ __launch_bounds__(256) void k_init(int* n_match, int* mg_min, double* acc, int* cnts) {
    int i = blockIdx.x * 256 + threadIdx.x;
    if (i < NB * NA) { n_match[i] = 0; mg_min[i] = 0x7fffffff; }
    if (i == 0) { acc[0] = 0.0; acc[1] = 0.0; cnts[0] = 0; cnts[1] = 0; }
}

// ---------------- decode + fg_anchor + best_gt ----------------
__global__ __launch_bounds__(256) void k_decode(
    const float* __restrict__ reg0, const float* __restrict__ obj0,
    const float* __restrict__ reg1, const float* __restrict__ obj1,
    const float* __restrict__ reg2, const float* __restrict__ obj2,
    const float* __restrict__ labels,
    float4* __restrict__ bbox, float* __restrict__ obj_logit,
    float* __restrict__ obj_cost, int* __restrict__ fg_anchor,
    int* __restrict__ best_gt)
{
    int b = blockIdx.y;
    int a = blockIdx.x * 256 + threadIdx.x;   // NA == 84*256 exactly
    __shared__ float lb[NG * 5];
    for (int i = threadIdx.x; i < NG * 5; i += 256) lb[i] = labels[b * NG * 5 + i];
    __syncthreads();

    int x, y; float xc, yc, s;
    anchor_xy(a, xc, yc, s, x, y);
    const float* regp; const float* objp; int hw, loc;
    if (a < NA0)       { regp = reg0; objp = obj0; hw = 16384; loc = y * 128 + x; }
    else if (a < NA01) { regp = reg1; objp = obj1; hw = 4096;  loc = y * 64  + x; }
    else               { regp = reg2; objp = obj2; hw = 1024;  loc = y * 32  + x; }
    float r0 = regp[(b * 4 + 0) * hw + loc];
    float r1 = regp[(b * 4 + 1) * hw + loc];
    float r2 = regp[(b * 4 + 2) * hw + loc];
    float r3 = regp[(b * 4 + 3) * hw + loc];
    float ol = objp[b * hw + loc];

    float px = (r0 + (float)x) * s, py = (r1 + (float)y) * s;
    float pw = expf(r2) * s,        ph = expf(r3) * s;

    // fg_anchor: any GT (including zeroed invalid ones, as in the reference)
    bool fga = false;
    for (int g = 0; g < NG; g++) {
        float gx = lb[g * 5 + 1], gy = lb[g * 5 + 2], gw = lb[g * 5 + 3], gh = lb[g * 5 + 4];
        float bl = xc - (gx - 0.5f * gw), br = (gx + 0.5f * gw) - xc;
        float bt = yc - (gy - 0.5f * gh), bb = (gy + 0.5f * gh) - yc;
        bool inb = fminf(fminf(bl, br), fminf(bt, bb)) > 0.f;
        float r = 2.5f * s;
        float cl = xc - (gx - r), cr = (gx + r) - xc;
        float ct = yc - (gy - r), cb = (gy + r) - yc;
        bool inc = fminf(fminf(cl, cr), fminf(ct, cb)) > 0.f;
        fga = fga || inb || inc;
    }

    float oc = softplusf(-ol);
    float pa = pw * ph;
    float p_tlx = px - 0.5f * pw, p_tly = py - 0.5f * ph;
    float p_brx = px + 0.5f * pw, p_bry = py + 0.5f * ph;

    // best_gt = argmin_g cost (strict < keeps first occurrence, like jnp.argmin)
    float bestc = 3.4e38f; int bg = 0;
    for (int g = 0; g < NG; g++) {
        float l0 = lb[g * 5 + 0], gx = lb[g * 5 + 1], gy = lb[g * 5 + 2];
        float gw = lb[g * 5 + 3], gh = lb[g * 5 + 4];
        bool gv = (l0 + gx + gy + gw + gh) > 0.f;
        float tlx = fmaxf(gx - 0.5f * gw, p_tlx), tly = fmaxf(gy - 0.5f * gh, p_tly);
        float brx = fminf(gx + 0.5f * gw, p_brx), bry = fminf(gy + 0.5f * gh, p_bry);
        bool en = (tlx < brx) && (tly < bry);
        float ai = en ? (brx - tlx) * (bry - tly) : 0.f;
        float iou = ai / (gw * gh + pa - ai + 1e-16f);
        float bl = xc - (gx - 0.5f * gw), br = (gx + 0.5f * gw) - xc;
        float bt = yc - (gy - 0.5f * gh), bb = (gy + 0.5f * gh) - yc;
        bool inb = fminf(fminf(bl, br), fminf(bt, bb)) > 0.f;
        float r = 2.5f * s;
        float cl = xc - (gx - r), cr = (gx + r) - xc;
        float ct = yc - (gy - r), cb = (gy + r) - yc;
        bool inc = fminf(fminf(cl, cr), fminf(ct, cb)) > 0.f;
        float c = oc + 3.0f * (-logf(iou + 1e-8f));
        if (!(inb && inc)) c += 100000.0f;
        if (!(gv && fga))  c += 10000000.0f;
        if (c < bestc) { bestc = c; bg = g; }
    }

    int idx = b * NA + a;
    bbox[idx]      = make_float4(px, py, pw, ph);
    obj_logit[idx] = ol;
    obj_cost[idx]  = oc;
    fg_anchor[idx] = fga ? 1 : 0;
    best_gt[idx]   = bg;
}

// ---------------- per-(b,g) top-k assignment ----------------
__global__ __launch_bounds__(256) void k_assign(
    const float* __restrict__ labels, const float4* __restrict__ bbox,
    const float* __restrict__ obj_cost, const int* __restrict__ fg_anchor,
    int* __restrict__ n_match, int* __restrict__ mg_min, int* __restrict__ cnts)
{
    int blk = blockIdx.x;
    int b = blk / NG, g = blk % NG;
    const float* L = labels + (b * NG + g) * 5;
    float l0 = L[0], gx = L[1], gy = L[2], gw = L[3], gh = L[4];
    bool gv = (l0 + gx + gy + gw + gh) > 0.f;
    if (!gv) return;                       // whole block exits uniformly
    int tid = threadIdx.x;
    if (tid == 0) atomicAdd(&cnts[1], 1);  // num_gts

    float g_tlx = gx - 0.5f * gw, g_tly = gy - 0.5f * gh;
    float g_brx = gx + 0.5f * gw, g_bry = gy + 0.5f * gh;
    float ag = gw * gh;
    float r8 = 2.5f;   // radius multiplier applied per-anchor below

    // per-thread top-NC smallest (cost, idx) and top-NC largest iou_m
    float tc[NC]; int ti[NC]; float tio[NC];
    #pragma unroll
    for (int k = 0; k < NC; k++) { tc[k] = 3.4e38f; ti[k] = 0x7fffffff; tio[k] = -1.f; }

    for (int a = tid; a < NA; a += 256) {
        int idx = b * NA + a;
        float4 p = bbox[idx];
        float pa = p.z * p.w;
        float tlx = fmaxf(g_tlx, p.x - 0.5f * p.z), tly = fmaxf(g_tly, p.y - 0.5f * p.w);
        float brx = fminf(g_brx, p.x + 0.5f * p.z), bry = fminf(g_bry, p.y + 0.5f * p.w);
        bool en = (tlx < brx) && (tly < bry);
        float ai = en ? (brx - tlx) * (bry - tly) : 0.f;
        float iou = ai / (ag + pa - ai + 1e-16f);
        int fga = fg_anchor[idx];
        float iom = fga ? iou : 0.f;

        int x, y; float xc, yc, s;
        anchor_xy(a, xc, yc, s, x, y);
        float bl = xc - g_tlx, br = g_brx - xc, bt = yc - g_tly, bb = g_bry - yc;
        bool inb = fminf(fminf(bl, br), fminf(bt, bb)) > 0.f;
        float r = r8 * s;
        float cl = xc - (gx - r), cr = (gx + r) - xc;
        float ct = yc - (gy - r), cb = (gy + r) - yc;
        bool inc = fminf(fminf(cl, cr), fminf(ct, cb)) > 0.f;

        float c = obj_cost[idx] + 3.0f * (-logf(iou + 1e-8f));
        if (!(inb && inc)) c += 100000.0f;
        if (!fga)          c += 10000000.0f;   // valid_pair = gv && fga; gv true here

        // insert into sorted-ascending (cost, idx); stable ties by smaller idx
        if (c < tc[NC - 1] || (c == tc[NC - 1] && a < ti[NC - 1])) {
            tc[NC - 1] = c; ti[NC - 1] = a;
            #pragma unroll
            for (int j = NC - 1; j > 0; --j) {
                bool sw = (tc[j] < tc[j - 1]) || (tc[j] == tc[j - 1] && ti[j] < ti[j - 1]);
                if (sw) {
                    float t1 = tc[j]; tc[j] = tc[j - 1]; tc[j - 1] = t1;
                    int   t2 = ti[j]; ti[j] = ti[j - 1]; ti[j - 1] = t2;
                }
            }
        }
        // insert into sorted-descending iou list
        if (iom > tio[NC - 1]) {
            tio[NC - 1] = iom;
            #pragma unroll
            for (int j = NC - 1; j > 0; --j) {
                if (tio[j] > tio[j - 1]) { float t = tio[j]; tio[j] = tio[j - 1]; tio[j - 1] = t; }
            }
        }
    }

    __shared__ float sc[256 * NC];
    __shared__ int   si[256 * NC];
    __shared__ float sio[256 * NC];
    #pragma unroll
    for (int k = 0; k < NC; k++) { sc[tid * NC + k] = tc[k]; si[tid * NC + k] = ti[k]; sio[tid * NC + k] = tio[k]; }
    __syncthreads();

    for (int off = 128; off > 0; off >>= 1) {
        if (tid < off) {
            int abase = tid * NC, bbase = (tid + off) * NC;
            int i = 0, j = 0;
            float oc_[NC]; int oi_[NC];
            #pragma unroll
            for (int k = 0; k < NC; k++) {
                float ca = sc[abase + i], cb2 = sc[bbase + j];
                int   ia = si[abase + i], ib  = si[bbase + j];
                bool ta = (ca < cb2) || (ca == cb2 && ia <= ib);
                oc_[k] = ta ? ca : cb2; oi_[k] = ta ? ia : ib;
                i += ta ? 1 : 0; j += ta ? 0 : 1;
            }
            float oo_[NC]; i = 0; j = 0;
            #pragma unroll
            for (int k = 0; k < NC; k++) {
                float va = sio[abase + i], vb = sio[bbase + j];
                bool ta = va >= vb;
                oo_[k] = ta ? va : vb;
                i += ta ? 1 : 0; j += ta ? 0 : 1;
            }
            #pragma unroll
            for (int k = 0; k < NC; k++) { sc[abase + k] = oc_[k]; si[abase + k] = oi_[k]; sio[abase + k] = oo_[k]; }
        }
        __syncthreads();
    }

    if (tid == 0) {
        float s10 = 0.f;
        #pragma unroll
        for (int k = 0; k < NC; k++) s10 += sio[k];   // descending order, like top_k().sum()
        int dk = (int)s10;                            // truncation toward zero, like astype(int32)
        if (dk < 1) dk = 1;
        if (dk > NC) dk = NC;
        for (int k = 0; k < dk; k++) {
            int aa = si[k];
            atomicAdd(&n_match[b * NA + aa], 1);
            atomicMin(&mg_min[b * NA + aa], g);
        }
    }
}

// ---------------- resolution + loss reduction ----------------
__global__ __launch_bounds__(256) void k_loss(
    const float* __restrict__ labels, const float4* __restrict__ bbox,
    const float* __restrict__ obj_logit, const int* __restrict__ n_match,
    const int* __restrict__ mg_min, const int* __restrict__ best_gt,
    double* __restrict__ acc, int* __restrict__ cnts)
{
    int b = blockIdx.y;
    int a = blockIdx.x * 256 + threadIdx.x;
    int idx = b * NA + a;
    float ol = obj_logit[idx];
    int n = n_match[idx];
    bool fg = false; int mg = 0;
    if (n == 1) { fg = true; mg = mg_min[idx]; }
    else if (n > 1) {
        int bg = best_gt[idx];
        const float* L = labels + (b * NG + bg) * 5;
        bool gvv = (L[0] + L[1] + L[2] + L[3] + L[4]) > 0.f;
        if (gvv) { fg = true; mg = bg; }
    }

    float objl = softplusf(ol) - (fg ? ol : 0.f);
    float il = 0.f;
    if (fg) {
        float4 p = bbox[idx];
        const float* L = labels + (b * NG + mg) * 5;
        float gx = L[1], gy = L[2], gw = L[3], gh = L[4];
        float tlx = fmaxf(p.x - 0.5f * p.z, gx - 0.5f * gw);
        float tly = fmaxf(p.y - 0.5f * p.w, gy - 0.5f * gh);
        float brx = fminf(p.x + 0.5f * p.z, gx + 0.5f * gw);
        float bry = fminf(p.y + 0.5f * p.w, gy + 0.5f * gh);
        bool en = (tlx < brx) && (tly < bry);
        float ai = en ? (brx - tlx) * (bry - tly) : 0.f;
        float iou = ai / (p.z * p.w + gw * gh - ai + 1e-16f);
        il = 1.f - iou * iou;
    }
    int nf = fg ? 1 : 0;

    // wave-64 reduce
    for (int off = 32; off > 0; off >>= 1) {
        objl += __shfl_down(objl, off);
        il   += __shfl_down(il, off);
        nf   += __shfl_down(nf, off);
    }
    if ((threadIdx.x & 63) == 0) {
        atomicAdd(&acc[0], (double)il);
        atomicAdd(&acc[1], (double)objl);
        atomicAdd(&cnts[0], nf);
    }
}

// ---------------- finalize ----------------
__global__ void k_fin(const double* __restrict__ acc, const int* __restrict__ cnts,
                      float* __restrict__ out)
{
    if (threadIdx.x == 0 && blockIdx.x == 0) {
        float nfg = (float)cnts[0], ngt = (float)cnts[1];
        float num_fg  = fmaxf(nfg, 1.f);
        float num_gts = fmaxf(ngt, 1.f);
        float li = (float)(acc[0] / (double)num_fg);
        float lo = (float)(acc[1] / (double)num_fg);
        out[0] = 5.f * li + lo;
        out[1] = 5.f * li;
        out[2] = lo;
        out[3] = 0.f;
        out[4] = num_fg / num_gts;
    }
}

extern "C" void kernel_launch(void* const* d_in, const int* in_sizes, int n_in,
                              void* d_out, int out_size, void* d_ws, size_t ws_size,
                              hipStream_t stream)
{
    // setup_inputs() dict order: reg0, obj0, reg1, obj1, reg2, obj2, labels
    const float* reg0   = (const float*)d_in[0];
    const float* obj0   = (const float*)d_in[1];
    const float* reg1   = (const float*)d_in[2];
    const float* obj1   = (const float*)d_in[3];
    const float* reg2   = (const float*)d_in[4];
    const float* obj2   = (const float*)d_in[5];
    const float* labels = (const float*)d_in[6];
    float* out = (float*)d_out;

    char* w = (char*)d_ws;
    double* acc = (double*)w;           // 16 B
    int*    cnts = (int*)(w + 16);      // 8 B
    size_t off = 32;
    float4* bbox      = (float4*)(w + off); off += (size_t)NB * NA * 16;
    float*  obj_logit = (float*)(w + off);  off += (size_t)NB * NA * 4;
    float*  obj_cost  = (float*)(w + off);  off += (size_t)NB * NA * 4;
    int*    fg_anchor = (int*)(w + off);    off += (size_t)NB * NA * 4;
    int*    n_match   = (int*)(w + off);    off += (size_t)NB * NA * 4;
    int*    mg_min    = (int*)(w + off);    off += (size_t)NB * NA * 4;
    int*    best_gt   = (int*)(w + off);    off += (size_t)NB * NA * 4;

    dim3 gA(NA / 256, NB);   // NA == 84*256 exactly

    k_init<<<dim3((NB * NA + 255) / 256), 256, 0, stream>>>(n_match, mg_min, acc, cnts);
    k_decode<<<gA, 256, 0, stream>>>(reg0, obj0, reg1, obj1, reg2, obj2, labels,
                                     bbox, obj_logit, obj_cost, fg_anchor, best_gt);
    k_assign<<<dim3(NB * NG), 256, 0, stream>>>(labels, bbox, obj_cost, fg_anchor,
                                                n_match, mg_min, cnts);
    k_loss<<<gA, 256, 0, stream>>>(labels, bbox, obj_logit, n_match, mg_min, best_gt,
                                   acc, cnts);
    k_fin<<<1, 64, 0, stream>>>(acc, cnts, out);
}

// Round 2
// 450.803 us; speedup vs baseline: 1.3668x; 1.3668x over previous
//
#include <hip/hip_runtime.h>
#include <math.h>

#define NA   21504   // 128^2 + 64^2 + 32^2
#define NA0  16384
#define NA01 20480
#define NG   100
#define NB   16
#define NC   10      // N_CAND

__device__ __forceinline__ float softplusf(float x) {
    // jax.nn.softplus == max(x,0) + log1p(exp(-|x|))
    return fmaxf(x, 0.f) + log1pf(expf(-fabsf(x)));
}

// ---------------- init scratch ----------------
__global__ __launch_bounds__(256) void k_init(int* n_match, int* mg_min, int* ccount,
                                              double* acc, int* cnts) {
    int i = blockIdx.x * 256 + threadIdx.x;
    if (i < NB * NA) { n_match[i] = 0; mg_min[i] = 0x7fffffff; }
    if (i < NB) ccount[i] = 0;
    if (i == 0) { acc[0] = 0.0; acc[1] = 0.0; cnts[0] = 0; cnts[1] = 0; }
}

// ---------------- decode + fg_anchor + compaction ----------------
// A0 = (p_tlx, p_tly, p_brx, p_bry)   predicted box corners
// A1 = (area_p, obj_cost, xc, yc)
__global__ __launch_bounds__(256) void k_decode(
    const float* __restrict__ reg0, const float* __restrict__ obj0,
    const float* __restrict__ reg1, const float* __restrict__ obj1,
    const float* __restrict__ reg2, const float* __restrict__ obj2,
    const float* __restrict__ labels,
    float4* __restrict__ A0, float4* __restrict__ A1,
    int* __restrict__ cidx, int* __restrict__ ccount)
{
    int b = blockIdx.y;
    int a = blockIdx.x * 256 + threadIdx.x;   // NA == 84*256; each block is one stride level
    int tid = threadIdx.x;

    int x, y, hw, loc; float s;
    const float* regp; const float* objp;
    if (a < NA0)       { x = a & 127;           y = a >> 7; s = 8.f;  hw = 16384; loc = y * 128 + x; regp = reg0; objp = obj0; }
    else if (a < NA01) { int i = a - NA0;  x = i & 63; y = i >> 6; s = 16.f; hw = 4096;  loc = y * 64 + x;  regp = reg1; objp = obj1; }
    else               { int i = a - NA01; x = i & 31; y = i >> 5; s = 32.f; hw = 1024;  loc = y * 32 + x;  regp = reg2; objp = obj2; }
    float xc = ((float)x + 0.5f) * s;
    float yc = ((float)y + 0.5f) * s;
    float r  = 2.5f * s;   // block-uniform

    // Per-GT precompute in LDS: tlx,tly,brx,bry, gx-r, gx+r, gy-r, gy+r
    __shared__ float lg[NG][8];
    for (int g = tid; g < NG; g += 256) {
        const float* L = labels + (b * NG + g) * 5;
        float gx = L[1], gy = L[2], gw = L[3], gh = L[4];
        lg[g][0] = gx - 0.5f * gw;
        lg[g][1] = gy - 0.5f * gh;
        lg[g][2] = gx + 0.5f * gw;
        lg[g][3] = gy + 0.5f * gh;
        lg[g][4] = gx - r;
        lg[g][5] = gx + r;
        lg[g][6] = gy - r;
        lg[g][7] = gy + r;
    }
    __syncthreads();

    float r0 = regp[(b * 4 + 0) * hw + loc];
    float r1 = regp[(b * 4 + 1) * hw + loc];
    float r2 = regp[(b * 4 + 2) * hw + loc];
    float r3 = regp[(b * 4 + 3) * hw + loc];
    float ol = objp[b * hw + loc];

    float px = (r0 + (float)x) * s, py = (r1 + (float)y) * s;
    float pw = expf(r2) * s,        ph = expf(r3) * s;

    // fg_anchor over all 100 GT rows (including zeroed invalid rows, per reference)
    bool fga = false;
    #pragma unroll 4
    for (int g = 0; g < NG; g++) {
        float bl = xc - lg[g][0], br = lg[g][2] - xc;
        float bt = yc - lg[g][1], bb = lg[g][3] - yc;
        float m1 = fminf(fminf(bl, br), fminf(bt, bb));
        float cl = xc - lg[g][4], cr = lg[g][5] - xc;
        float ct = yc - lg[g][6], cb = lg[g][7] - yc;
        float m2 = fminf(fminf(cl, cr), fminf(ct, cb));
        fga = fga || (fmaxf(m1, m2) > 0.f);
    }

    int idx = b * NA + a;
    A0[idx] = make_float4(px - 0.5f * pw, py - 0.5f * ph, px + 0.5f * pw, py + 0.5f * ph);
    A1[idx] = make_float4(pw * ph, softplusf(-ol), xc, yc);

    // wave-ballot compaction of fg anchors into cidx[b]
    unsigned long long mask = __ballot(fga);
    if (fga) {
        int lane = tid & 63;
        int prefix = __popcll(mask & ((1ull << lane) - 1ull));
        int first  = __ffsll(mask) - 1;
        int base = 0;
        if (lane == first) base = atomicAdd(&ccount[b], __popcll(mask));
        base = __shfl(base, first, 64);
        cidx[b * NA + base + prefix] = a;
    }
}

// ---------------- per-(b,g) top-k assignment over compacted fg anchors ----------------
__global__ __launch_bounds__(256) void k_assign(
    const float* __restrict__ labels, const float4* __restrict__ A0,
    const float4* __restrict__ A1, const int* __restrict__ cidx,
    const int* __restrict__ ccount,
    int* __restrict__ n_match, int* __restrict__ mg_min, int* __restrict__ cnts)
{
    int blk = blockIdx.x;
    int b = blk / NG, g = blk % NG;
    const float* L = labels + (b * NG + g) * 5;
    float l0 = L[0], gx = L[1], gy = L[2], gw = L[3], gh = L[4];
    bool gv = (l0 + gx + gy + gw + gh) > 0.f;
    if (!gv) return;                       // whole block exits uniformly
    int tid = threadIdx.x;
    if (tid == 0) atomicAdd(&cnts[1], 1);  // num_gts

    float g_tlx = gx - 0.5f * gw, g_tly = gy - 0.5f * gh;
    float g_brx = gx + 0.5f * gw, g_bry = gy + 0.5f * gh;
    float ag = gw * gh;

    int cnt = ccount[b];
    int bbase = b * NA;

    // per-thread top-NC smallest (cost, idx) and top-NC largest iou
    float tc[NC]; int ti[NC]; float tio[NC];
    #pragma unroll
    for (int k = 0; k < NC; k++) { tc[k] = 3.4e38f; ti[k] = 0x7fffffff; tio[k] = 0.f; }

    for (int m = tid; m < cnt; m += 256) {
        int a = cidx[bbase + m];
        float4 c0 = A0[bbase + a];
        float4 c1 = A1[bbase + a];
        float tlx = fmaxf(g_tlx, c0.x), tly = fmaxf(g_tly, c0.y);
        float brx = fminf(g_brx, c0.z), bry = fminf(g_bry, c0.w);
        bool en = (tlx < brx) && (tly < bry);
        float ai = en ? (brx - tlx) * (bry - tly) : 0.f;
        float iou = ai / (ag + c1.x - ai + 1e-16f);

        // top-NC iou (all compacted anchors are fga; this g is valid → ious_m = iou)
        if (iou > tio[NC - 1]) {
            tio[NC - 1] = iou;
            #pragma unroll
            for (int j = NC - 1; j > 0; --j) {
                if (tio[j] > tio[j - 1]) { float t = tio[j]; tio[j] = tio[j - 1]; tio[j - 1] = t; }
            }
        }

        float xcA = c1.z, ycA = c1.w;
        float bl = xcA - g_tlx, brr = g_brx - xcA;
        float bt = ycA - g_tly, bbb = g_bry - ycA;
        bool inb = fminf(fminf(bl, brr), fminf(bt, bbb)) > 0.f;
        float rr = (a < NA0) ? 20.f : ((a < NA01) ? 40.f : 80.f);
        float cl = xcA - (gx - rr), cr2 = (gx + rr) - xcA;
        float ct = ycA - (gy - rr), cb2 = (gy + rr) - ycA;
        bool inc = fminf(fminf(cl, cr2), fminf(ct, cb2)) > 0.f;

        float c = c1.y + 3.0f * (-__logf(iou + 1e-8f));
        if (!(inb && inc)) c += 100000.0f;
        // valid_pair == true for compacted anchors with valid g → +0

        if (c < tc[NC - 1] || (c == tc[NC - 1] && a < ti[NC - 1])) {
            tc[NC - 1] = c; ti[NC - 1] = a;
            #pragma unroll
            for (int j = NC - 1; j > 0; --j) {
                bool sw = (tc[j] < tc[j - 1]) || (tc[j] == tc[j - 1] && ti[j] < ti[j - 1]);
                if (sw) {
                    float t1 = tc[j]; tc[j] = tc[j - 1]; tc[j - 1] = t1;
                    int   t2 = ti[j]; ti[j] = ti[j - 1]; ti[j - 1] = t2;
                }
            }
        }
    }

    __shared__ float sc[256 * NC];
    __shared__ int   si[256 * NC];
    __shared__ float sio[256 * NC];
    #pragma unroll
    for (int k = 0; k < NC; k++) { sc[tid * NC + k] = tc[k]; si[tid * NC + k] = ti[k]; sio[tid * NC + k] = tio[k]; }
    __syncthreads();

    for (int off = 128; off > 0; off >>= 1) {
        if (tid < off) {
            int abase = tid * NC, bb2 = (tid + off) * NC;
            int i = 0, j = 0;
            float oc_[NC]; int oi_[NC];
            #pragma unroll
            for (int k = 0; k < NC; k++) {
                float ca = sc[abase + i], cb3 = sc[bb2 + j];
                int   ia = si[abase + i], ib  = si[bb2 + j];
                bool ta = (ca < cb3) || (ca == cb3 && ia <= ib);
                oc_[k] = ta ? ca : cb3; oi_[k] = ta ? ia : ib;
                i += ta ? 1 : 0; j += ta ? 0 : 1;
            }
            float oo_[NC]; i = 0; j = 0;
            #pragma unroll
            for (int k = 0; k < NC; k++) {
                float va = sio[abase + i], vb = sio[bb2 + j];
                bool ta = va >= vb;
                oo_[k] = ta ? va : vb;
                i += ta ? 1 : 0; j += ta ? 0 : 1;
            }
            #pragma unroll
            for (int k = 0; k < NC; k++) { sc[abase + k] = oc_[k]; si[abase + k] = oi_[k]; sio[abase + k] = oo_[k]; }
        }
        __syncthreads();
    }

    if (tid == 0) {
        float s10 = 0.f;
        #pragma unroll
        for (int k = 0; k < NC; k++) s10 += sio[k];   // descending, like top_k().sum()
        int dk = (int)s10;                            // truncation, like astype(int32)
        if (dk < 1) dk = 1;
        if (dk > NC) dk = NC;
        for (int k = 0; k < dk; k++) {
            int aa = si[k];
            atomicAdd(&n_match[bbase + aa], 1);
            atomicMin(&mg_min[bbase + aa], g);
        }
    }
}

// ---------------- resolution (lazy best_gt) + loss reduction ----------------
__global__ __launch_bounds__(256) void k_loss(
    const float* __restrict__ labels,
    const float* __restrict__ obj0, const float* __restrict__ obj1,
    const float* __restrict__ obj2,
    const float4* __restrict__ A0, const float4* __restrict__ A1,
    const int* __restrict__ n_match, const int* __restrict__ mg_min,
    double* __restrict__ acc, int* __restrict__ cnts)
{
    int b = blockIdx.y;
    int a = blockIdx.x * 256 + threadIdx.x;
    int idx = b * NA + a;
    int tid = threadIdx.x;

    __shared__ float lbl[NG * 5];
    for (int i = tid; i < NG * 5; i += 256) lbl[i] = labels[b * NG * 5 + i];
    __syncthreads();

    // reload obj logit from inputs
    int x, y, hw, loc;
    const float* objp;
    float rr;
    if (a < NA0)       { x = a & 127;           y = a >> 7; hw = 16384; loc = y * 128 + x; objp = obj0; rr = 20.f; }
    else if (a < NA01) { int i = a - NA0;  x = i & 63; y = i >> 6; hw = 4096;  loc = y * 64 + x;  objp = obj1; rr = 40.f; }
    else               { int i = a - NA01; x = i & 31; y = i >> 5; hw = 1024;  loc = y * 32 + x;  objp = obj2; rr = 80.f; }
    float ol = objp[b * hw + loc];

    int n = n_match[idx];
    bool fg = false; int mg = 0;
    if (n == 1) { fg = true; mg = mg_min[idx]; }
    else if (n > 1) {
        // lazy best_gt = argmin_g cost (rare lanes)
        float4 c0 = A0[idx]; float4 c1 = A1[idx];
        float pa = c1.x, oc = c1.y, xcA = c1.z, ycA = c1.w;
        float bestc = 3.4e38f; int bg = 0;
        for (int g = 0; g < NG; g++) {
            float l0 = lbl[g * 5 + 0], gx = lbl[g * 5 + 1], gy = lbl[g * 5 + 2];
            float gw = lbl[g * 5 + 3], gh = lbl[g * 5 + 4];
            bool gvv = (l0 + gx + gy + gw + gh) > 0.f;
            float tlx = fmaxf(gx - 0.5f * gw, c0.x), tly = fmaxf(gy - 0.5f * gh, c0.y);
            float brx = fminf(gx + 0.5f * gw, c0.z), bry = fminf(gy + 0.5f * gh, c0.w);
            bool en = (tlx < brx) && (tly < bry);
            float ai = en ? (brx - tlx) * (bry - tly) : 0.f;
            float iou = ai / (gw * gh + pa - ai + 1e-16f);
            float bl = xcA - (gx - 0.5f * gw), br = (gx + 0.5f * gw) - xcA;
            float bt = ycA - (gy - 0.5f * gh), bb = (gy + 0.5f * gh) - ycA;
            bool inb = fminf(fminf(bl, br), fminf(bt, bb)) > 0.f;
            float cl = xcA - (gx - rr), cr = (gx + rr) - xcA;
            float ct = ycA - (gy - rr), cb = (gy + rr) - ycA;
            bool inc = fminf(fminf(cl, cr), fminf(ct, cb)) > 0.f;
            float c = oc + 3.0f * (-__logf(iou + 1e-8f));
            if (!(inb && inc)) c += 100000.0f;
            if (!gvv)          c += 10000000.0f;   // n>1 anchors are always fg_anchor
            if (c < bestc) { bestc = c; bg = g; }
        }
        bool gvv = (lbl[bg * 5 + 0] + lbl[bg * 5 + 1] + lbl[bg * 5 + 2] +
                    lbl[bg * 5 + 3] + lbl[bg * 5 + 4]) > 0.f;
        if (gvv) { fg = true; mg = bg; }
    }

    float objl = softplusf(ol) - (fg ? ol : 0.f);
    float il = 0.f;
    if (fg) {
        float4 c0 = A0[idx]; float4 c1 = A1[idx];
        float gx = lbl[mg * 5 + 1], gy = lbl[mg * 5 + 2];
        float gw = lbl[mg * 5 + 3], gh = lbl[mg * 5 + 4];
        float tlx = fmaxf(c0.x, gx - 0.5f * gw);
        float tly = fmaxf(c0.y, gy - 0.5f * gh);
        float brx = fminf(c0.z, gx + 0.5f * gw);
        float bry = fminf(c0.w, gy + 0.5f * gh);
        bool en = (tlx < brx) && (tly < bry);
        float ai = en ? (brx - tlx) * (bry - tly) : 0.f;
        float iou = ai / (c1.x + gw * gh - ai + 1e-16f);
        il = 1.f - iou * iou;
    }
    int nf = fg ? 1 : 0;

    for (int off = 32; off > 0; off >>= 1) {
        objl += __shfl_down(objl, off);
        il   += __shfl_down(il, off);
        nf   += __shfl_down(nf, off);
    }
    if ((tid & 63) == 0) {
        atomicAdd(&acc[0], (double)il);
        atomicAdd(&acc[1], (double)objl);
        atomicAdd(&cnts[0], nf);
    }
}

// ---------------- finalize ----------------
__global__ void k_fin(const double* __restrict__ acc, const int* __restrict__ cnts,
                      float* __restrict__ out)
{
    if (threadIdx.x == 0 && blockIdx.x == 0) {
        float nfg = (float)cnts[0], ngt = (float)cnts[1];
        float num_fg  = fmaxf(nfg, 1.f);
        float num_gts = fmaxf(ngt, 1.f);
        float li = (float)(acc[0] / (double)num_fg);
        float lo = (float)(acc[1] / (double)num_fg);
        out[0] = 5.f * li + lo;
        out[1] = 5.f * li;
        out[2] = lo;
        out[3] = 0.f;
        out[4] = num_fg / num_gts;
    }
}

extern "C" void kernel_launch(void* const* d_in, const int* in_sizes, int n_in,
                              void* d_out, int out_size, void* d_ws, size_t ws_size,
                              hipStream_t stream)
{
    const float* reg0   = (const float*)d_in[0];
    const float* obj0   = (const float*)d_in[1];
    const float* reg1   = (const float*)d_in[2];
    const float* obj1   = (const float*)d_in[3];
    const float* reg2   = (const float*)d_in[4];
    const float* obj2   = (const float*)d_in[5];
    const float* labels = (const float*)d_in[6];
    float* out = (float*)d_out;

    char* w = (char*)d_ws;
    double* acc  = (double*)w;            // 16 B
    int*    cnts = (int*)(w + 16);        // 8 B
    int*    ccount = (int*)(w + 64);      // NB ints
    size_t off = 128;
    float4* A0      = (float4*)(w + off); off += (size_t)NB * NA * 16;
    float4* A1      = (float4*)(w + off); off += (size_t)NB * NA * 16;
    int*    cidx    = (int*)(w + off);    off += (size_t)NB * NA * 4;
    int*    n_match = (int*)(w + off);    off += (size_t)NB * NA * 4;
    int*    mg_min  = (int*)(w + off);    off += (size_t)NB * NA * 4;

    dim3 gA(NA / 256, NB);   // 84 x 16

    k_init<<<dim3((NB * NA + 255) / 256), 256, 0, stream>>>(n_match, mg_min, ccount, acc, cnts);
    k_decode<<<gA, 256, 0, stream>>>(reg0, obj0, reg1, obj1, reg2, obj2, labels,
                                     A0, A1, cidx, ccount);
    k_assign<<<dim3(NB * NG), 256, 0, stream>>>(labels, A0, A1, cidx, ccount,
                                                n_match, mg_min, cnts);
    k_loss<<<gA, 256, 0, stream>>>(labels, obj0, obj1, obj2, A0, A1,
                                   n_match, mg_min, acc, cnts);
    k_fin<<<1, 64, 0, stream>>>(acc, cnts, out);
}

// Round 4
// 302.309 us; speedup vs baseline: 2.0382x; 1.4912x over previous
//
#include <hip/hip_runtime.h>
#include <math.h>

#define NA   21504   // 128^2 + 64^2 + 32^2
#define NA0  16384
#define NA01 20480
#define NG   100
#define NB   16
#define NC   10      // N_CAND
#define NBLK 1344    // k_loss blocks = 84 * 16

__device__ __forceinline__ float softplusf(float x) {
    // jax.nn.softplus == max(x,0) + log1p(exp(-|x|))
    return fmaxf(x, 0.f) + log1pf(expf(-fabsf(x)));
}

// ---------------- init scratch ----------------
__global__ __launch_bounds__(256) void k_init(int* n_match, int* mg_min, int* ccount) {
    int i = blockIdx.x * 256 + threadIdx.x;
    if (i < NB * NA) { n_match[i] = 0; mg_min[i] = 0x7fffffff; }
    if (i < NB) ccount[i] = 0;
}

// ---------------- decode + fg_anchor + compaction ----------------
// A0 = (p_tlx, p_tly, p_brx, p_bry)   predicted box corners
// A1 = (area_p, obj_cost, xc, yc)
__global__ __launch_bounds__(256) void k_decode(
    const float* __restrict__ reg0, const float* __restrict__ obj0,
    const float* __restrict__ reg1, const float* __restrict__ obj1,
    const float* __restrict__ reg2, const float* __restrict__ obj2,
    const float* __restrict__ labels,
    float4* __restrict__ A0, float4* __restrict__ A1,
    int* __restrict__ cidx, int* __restrict__ ccount)
{
    int b = blockIdx.y;
    int a = blockIdx.x * 256 + threadIdx.x;   // NA == 84*256; each block is one stride level
    int tid = threadIdx.x;

    int x, y, hw, loc; float s;
    const float* regp; const float* objp;
    if (a < NA0)       { x = a & 127;           y = a >> 7; s = 8.f;  hw = 16384; loc = y * 128 + x; regp = reg0; objp = obj0; }
    else if (a < NA01) { int i = a - NA0;  x = i & 63; y = i >> 6; s = 16.f; hw = 4096;  loc = y * 64 + x;  regp = reg1; objp = obj1; }
    else               { int i = a - NA01; x = i & 31; y = i >> 5; s = 32.f; hw = 1024;  loc = y * 32 + x;  regp = reg2; objp = obj2; }
    float xc = ((float)x + 0.5f) * s;
    float yc = ((float)y + 0.5f) * s;
    float r  = 2.5f * s;   // block-uniform

    // Per-GT precompute in LDS: tlx,tly,brx,bry, gx-r, gx+r, gy-r, gy+r
    __shared__ float lg[NG][8];
    for (int g = tid; g < NG; g += 256) {
        const float* L = labels + (b * NG + g) * 5;
        float gx = L[1], gy = L[2], gw = L[3], gh = L[4];
        lg[g][0] = gx - 0.5f * gw;
        lg[g][1] = gy - 0.5f * gh;
        lg[g][2] = gx + 0.5f * gw;
        lg[g][3] = gy + 0.5f * gh;
        lg[g][4] = gx - r;
        lg[g][5] = gx + r;
        lg[g][6] = gy - r;
        lg[g][7] = gy + r;
    }
    __syncthreads();

    float r0 = regp[(b * 4 + 0) * hw + loc];
    float r1 = regp[(b * 4 + 1) * hw + loc];
    float r2 = regp[(b * 4 + 2) * hw + loc];
    float r3 = regp[(b * 4 + 3) * hw + loc];
    float ol = objp[b * hw + loc];

    float px = (r0 + (float)x) * s, py = (r1 + (float)y) * s;
    float pw = expf(r2) * s,        ph = expf(r3) * s;

    // fg_anchor over all 100 GT rows (including zeroed invalid rows, per reference)
    bool fga = false;
    #pragma unroll 4
    for (int g = 0; g < NG; g++) {
        float bl = xc - lg[g][0], br = lg[g][2] - xc;
        float bt = yc - lg[g][1], bb = lg[g][3] - yc;
        float m1 = fminf(fminf(bl, br), fminf(bt, bb));
        float cl = xc - lg[g][4], cr = lg[g][5] - xc;
        float ct = yc - lg[g][6], cb = lg[g][7] - yc;
        float m2 = fminf(fminf(cl, cr), fminf(ct, cb));
        fga = fga || (fmaxf(m1, m2) > 0.f);
    }

    int idx = b * NA + a;
    A0[idx] = make_float4(px - 0.5f * pw, py - 0.5f * ph, px + 0.5f * pw, py + 0.5f * ph);
    A1[idx] = make_float4(pw * ph, softplusf(-ol), xc, yc);

    // wave-ballot compaction of fg anchors into cidx[b]
    unsigned long long mask = __ballot(fga);
    if (fga) {
        int lane = tid & 63;
        int prefix = __popcll(mask & ((1ull << lane) - 1ull));
        int first  = __ffsll(mask) - 1;
        int base = 0;
        if (lane == first) base = atomicAdd(&ccount[b], __popcll(mask));
        base = __shfl(base, first, 64);
        cidx[b * NA + base + prefix] = a;
    }
}

// ---------------- per-(b,g) top-k assignment over compacted fg anchors ----------------
__global__ __launch_bounds__(256) void k_assign(
    const float* __restrict__ labels, const float4* __restrict__ A0,
    const float4* __restrict__ A1, const int* __restrict__ cidx,
    const int* __restrict__ ccount,
    int* __restrict__ n_match, int* __restrict__ mg_min)
{
    int blk = blockIdx.x;
    int b = blk / NG, g = blk % NG;
    const float* L = labels + (b * NG + g) * 5;
    float l0 = L[0], gx = L[1], gy = L[2], gw = L[3], gh = L[4];
    bool gv = (l0 + gx + gy + gw + gh) > 0.f;
    if (!gv) return;                       // whole block exits uniformly
    int tid = threadIdx.x;

    float g_tlx = gx - 0.5f * gw, g_tly = gy - 0.5f * gh;
    float g_brx = gx + 0.5f * gw, g_bry = gy + 0.5f * gh;
    float ag = gw * gh;

    int cnt = ccount[b];
    int bbase = b * NA;

    // per-thread top-NC smallest (cost, idx) and top-NC largest iou
    float tc[NC]; int ti[NC]; float tio[NC];
    #pragma unroll
    for (int k = 0; k < NC; k++) { tc[k] = 3.4e38f; ti[k] = 0x7fffffff; tio[k] = 0.f; }

    for (int m = tid; m < cnt; m += 256) {
        int a = cidx[bbase + m];
        float4 c0 = A0[bbase + a];
        float4 c1 = A1[bbase + a];
        float tlx = fmaxf(g_tlx, c0.x), tly = fmaxf(g_tly, c0.y);
        float brx = fminf(g_brx, c0.z), bry = fminf(g_bry, c0.w);
        bool en = (tlx < brx) && (tly < bry);
        float ai = en ? (brx - tlx) * (bry - tly) : 0.f;
        float iou = ai / (ag + c1.x - ai + 1e-16f);

        // top-NC iou (all compacted anchors are fga; this g is valid → ious_m = iou)
        if (iou > tio[NC - 1]) {
            tio[NC - 1] = iou;
            #pragma unroll
            for (int j = NC - 1; j > 0; --j) {
                if (tio[j] > tio[j - 1]) { float t = tio[j]; tio[j] = tio[j - 1]; tio[j - 1] = t; }
            }
        }

        float xcA = c1.z, ycA = c1.w;
        float bl = xcA - g_tlx, brr = g_brx - xcA;
        float bt = ycA - g_tly, bbb = g_bry - ycA;
        bool inb = fminf(fminf(bl, brr), fminf(bt, bbb)) > 0.f;
        float rr = (a < NA0) ? 20.f : ((a < NA01) ? 40.f : 80.f);
        float cl = xcA - (gx - rr), cr2 = (gx + rr) - xcA;
        float ct = ycA - (gy - rr), cb2 = (gy + rr) - ycA;
        bool inc = fminf(fminf(cl, cr2), fminf(ct, cb2)) > 0.f;

        float c = c1.y + 3.0f * (-__logf(iou + 1e-8f));
        if (!(inb && inc)) c += 100000.0f;
        // valid_pair == true for compacted anchors with valid g → +0

        if (c < tc[NC - 1] || (c == tc[NC - 1] && a < ti[NC - 1])) {
            tc[NC - 1] = c; ti[NC - 1] = a;
            #pragma unroll
            for (int j = NC - 1; j > 0; --j) {
                bool sw = (tc[j] < tc[j - 1]) || (tc[j] == tc[j - 1] && ti[j] < ti[j - 1]);
                if (sw) {
                    float t1 = tc[j]; tc[j] = tc[j - 1]; tc[j - 1] = t1;
                    int   t2 = ti[j]; ti[j] = ti[j - 1]; ti[j - 1] = t2;
                }
            }
        }
    }

    __shared__ float sc[256 * NC];
    __shared__ int   si[256 * NC];
    __shared__ float sio[256 * NC];
    #pragma unroll
    for (int k = 0; k < NC; k++) { sc[tid * NC + k] = tc[k]; si[tid * NC + k] = ti[k]; sio[tid * NC + k] = tio[k]; }
    __syncthreads();

    for (int off = 128; off > 0; off >>= 1) {
        if (tid < off) {
            int abase = tid * NC, bb2 = (tid + off) * NC;
            int i = 0, j = 0;
            float oc_[NC]; int oi_[NC];
            #pragma unroll
            for (int k = 0; k < NC; k++) {
                float ca = sc[abase + i], cb3 = sc[bb2 + j];
                int   ia = si[abase + i], ib  = si[bb2 + j];
                bool ta = (ca < cb3) || (ca == cb3 && ia <= ib);
                oc_[k] = ta ? ca : cb3; oi_[k] = ta ? ia : ib;
                i += ta ? 1 : 0; j += ta ? 0 : 1;
            }
            float oo_[NC]; i = 0; j = 0;
            #pragma unroll
            for (int k = 0; k < NC; k++) {
                float va = sio[abase + i], vb = sio[bb2 + j];
                bool ta = va >= vb;
                oo_[k] = ta ? va : vb;
                i += ta ? 1 : 0; j += ta ? 0 : 1;
            }
            #pragma unroll
            for (int k = 0; k < NC; k++) { sc[abase + k] = oc_[k]; si[abase + k] = oi_[k]; sio[abase + k] = oo_[k]; }
        }
        __syncthreads();
    }

    if (tid == 0) {
        float s10 = 0.f;
        #pragma unroll
        for (int k = 0; k < NC; k++) s10 += sio[k];   // descending, like top_k().sum()
        int dk = (int)s10;                            // truncation, like astype(int32)
        if (dk < 1) dk = 1;
        if (dk > NC) dk = NC;
        for (int k = 0; k < dk; k++) {
            int aa = si[k];
            atomicAdd(&n_match[bbase + aa], 1);
            atomicMin(&mg_min[bbase + aa], g);
        }
    }
}

// ---------------- resolution (lazy best_gt) + per-block partial sums ----------------
__global__ __launch_bounds__(256) void k_loss(
    const float* __restrict__ labels,
    const float* __restrict__ obj0, const float* __restrict__ obj1,
    const float* __restrict__ obj2,
    const float4* __restrict__ A0, const float4* __restrict__ A1,
    const int* __restrict__ n_match, const int* __restrict__ mg_min,
    float* __restrict__ pIl, float* __restrict__ pObj, int* __restrict__ pNf)
{
    int b = blockIdx.y;
    int a = blockIdx.x * 256 + threadIdx.x;
    int idx = b * NA + a;
    int tid = threadIdx.x;

    __shared__ float lbl[NG * 5];
    for (int i = tid; i < NG * 5; i += 256) lbl[i] = labels[b * NG * 5 + i];
    __syncthreads();

    // reload obj logit from inputs
    int x, y, hw, loc;
    const float* objp;
    float rr;
    if (a < NA0)       { x = a & 127;           y = a >> 7; hw = 16384; loc = y * 128 + x; objp = obj0; rr = 20.f; }
    else if (a < NA01) { int i = a - NA0;  x = i & 63; y = i >> 6; hw = 4096;  loc = y * 64 + x;  objp = obj1; rr = 40.f; }
    else               { int i = a - NA01; x = i & 31; y = i >> 5; hw = 1024;  loc = y * 32 + x;  objp = obj2; rr = 80.f; }
    float ol = objp[b * hw + loc];

    int n = n_match[idx];
    bool fg = false; int mg = 0;
    if (n == 1) { fg = true; mg = mg_min[idx]; }
    else if (n > 1) {
        // lazy best_gt = argmin_g cost (rare lanes)
        float4 c0 = A0[idx]; float4 c1 = A1[idx];
        float pa = c1.x, oc = c1.y, xcA = c1.z, ycA = c1.w;
        float bestc = 3.4e38f; int bg = 0;
        for (int g = 0; g < NG; g++) {
            float l0 = lbl[g * 5 + 0], gx = lbl[g * 5 + 1], gy = lbl[g * 5 + 2];
            float gw = lbl[g * 5 + 3], gh = lbl[g * 5 + 4];
            bool gvv = (l0 + gx + gy + gw + gh) > 0.f;
            float tlx = fmaxf(gx - 0.5f * gw, c0.x), tly = fmaxf(gy - 0.5f * gh, c0.y);
            float brx = fminf(gx + 0.5f * gw, c0.z), bry = fminf(gy + 0.5f * gh, c0.w);
            bool en = (tlx < brx) && (tly < bry);
            float ai = en ? (brx - tlx) * (bry - tly) : 0.f;
            float iou = ai / (gw * gh + pa - ai + 1e-16f);
            float bl = xcA - (gx - 0.5f * gw), br = (gx + 0.5f * gw) - xcA;
            float bt = ycA - (gy - 0.5f * gh), bb = (gy + 0.5f * gh) - ycA;
            bool inb = fminf(fminf(bl, br), fminf(bt, bb)) > 0.f;
            float cl = xcA - (gx - rr), cr = (gx + rr) - xcA;
            float ct = ycA - (gy - rr), cb = (gy + rr) - ycA;
            bool inc = fminf(fminf(cl, cr), fminf(ct, cb)) > 0.f;
            float c = oc + 3.0f * (-__logf(iou + 1e-8f));
            if (!(inb && inc)) c += 100000.0f;
            if (!gvv)          c += 10000000.0f;   // n>1 anchors are always fg_anchor
            if (c < bestc) { bestc = c; bg = g; }
        }
        bool gvv = (lbl[bg * 5 + 0] + lbl[bg * 5 + 1] + lbl[bg * 5 + 2] +
                    lbl[bg * 5 + 3] + lbl[bg * 5 + 4]) > 0.f;
        if (gvv) { fg = true; mg = bg; }
    }

    float objl = softplusf(ol) - (fg ? ol : 0.f);
    float il = 0.f;
    if (fg) {
        float4 c0 = A0[idx]; float4 c1 = A1[idx];
        float gx = lbl[mg * 5 + 1], gy = lbl[mg * 5 + 2];
        float gw = lbl[mg * 5 + 3], gh = lbl[mg * 5 + 4];
        float tlx = fmaxf(c0.x, gx - 0.5f * gw);
        float tly = fmaxf(c0.y, gy - 0.5f * gh);
        float brx = fminf(c0.z, gx + 0.5f * gw);
        float bry = fminf(c0.w, gy + 0.5f * gh);
        bool en = (tlx < brx) && (tly < bry);
        float ai = en ? (brx - tlx) * (bry - tly) : 0.f;
        float iou = ai / (c1.x + gw * gh - ai + 1e-16f);
        il = 1.f - iou * iou;
    }
    int nf = fg ? 1 : 0;

    // wave reduce, then LDS across the 4 waves, then ONE store per block (no atomics)
    for (int off = 32; off > 0; off >>= 1) {
        objl += __shfl_down(objl, off);
        il   += __shfl_down(il, off);
        nf   += __shfl_down(nf, off);
    }
    __shared__ float wIl[4], wObj[4];
    __shared__ int   wNf[4];
    int wid = tid >> 6;
    if ((tid & 63) == 0) { wIl[wid] = il; wObj[wid] = objl; wNf[wid] = nf; }
    __syncthreads();
    if (tid == 0) {
        float sIl = wIl[0] + wIl[1] + wIl[2] + wIl[3];
        float sObj = wObj[0] + wObj[1] + wObj[2] + wObj[3];
        int   sNf = wNf[0] + wNf[1] + wNf[2] + wNf[3];
        int pb = b * (NA / 256) + blockIdx.x;
        pIl[pb] = sIl; pObj[pb] = sObj; pNf[pb] = sNf;
    }
}

// ---------------- finalize: reduce partials + count gts ----------------
__global__ __launch_bounds__(256) void k_fin(
    const float* __restrict__ pIl, const float* __restrict__ pObj,
    const int* __restrict__ pNf, const float* __restrict__ labels,
    float* __restrict__ out)
{
    int tid = threadIdx.x;
    double dIl = 0.0, dObj = 0.0;
    int nf = 0;
    for (int i = tid; i < NBLK; i += 256) {
        dIl += (double)pIl[i];
        dObj += (double)pObj[i];
        nf += pNf[i];
    }
    int ng = 0;
    for (int i = tid; i < NB * NG; i += 256) {
        const float* L = labels + i * 5;
        if (L[0] + L[1] + L[2] + L[3] + L[4] > 0.f) ng++;
    }
    // wave reduce
    for (int off = 32; off > 0; off >>= 1) {
        dIl += __shfl_down(dIl, off);
        dObj += __shfl_down(dObj, off);
        nf += __shfl_down(nf, off);
        ng += __shfl_down(ng, off);
    }
    __shared__ double sIl[4], sObj[4];
    __shared__ int sNf[4], sNg[4];
    int wid = tid >> 6;
    if ((tid & 63) == 0) { sIl[wid] = dIl; sObj[wid] = dObj; sNf[wid] = nf; sNg[wid] = ng; }
    __syncthreads();
    if (tid == 0) {
        double tIl = sIl[0] + sIl[1] + sIl[2] + sIl[3];
        double tObj = sObj[0] + sObj[1] + sObj[2] + sObj[3];
        int tNf = sNf[0] + sNf[1] + sNf[2] + sNf[3];
        int tNg = sNg[0] + sNg[1] + sNg[2] + sNg[3];
        float num_fg  = fmaxf((float)tNf, 1.f);
        float num_gts = fmaxf((float)tNg, 1.f);
        float li = (float)(tIl / (double)num_fg);
        float lo = (float)(tObj / (double)num_fg);
        out[0] = 5.f * li + lo;
        out[1] = 5.f * li;
        out[2] = lo;
        out[3] = 0.f;
        out[4] = num_fg / num_gts;
    }
}

extern "C" void kernel_launch(void* const* d_in, const int* in_sizes, int n_in,
                              void* d_out, int out_size, void* d_ws, size_t ws_size,
                              hipStream_t stream)
{
    const float* reg0   = (const float*)d_in[0];
    const float* obj0   = (const float*)d_in[1];
    const float* reg1   = (const float*)d_in[2];
    const float* obj1   = (const float*)d_in[3];
    const float* reg2   = (const float*)d_in[4];
    const float* obj2   = (const float*)d_in[5];
    const float* labels = (const float*)d_in[6];
    float* out = (float*)d_out;

    char* w = (char*)d_ws;
    int*    ccount = (int*)w;             // NB ints
    size_t off = 256;
    float*  pIl  = (float*)(w + off); off += NBLK * 4;
    float*  pObj = (float*)(w + off); off += NBLK * 4;
    int*    pNf  = (int*)(w + off);   off += NBLK * 4;
    off = (off + 255) & ~(size_t)255;
    float4* A0      = (float4*)(w + off); off += (size_t)NB * NA * 16;
    float4* A1      = (float4*)(w + off); off += (size_t)NB * NA * 16;
    int*    cidx    = (int*)(w + off);    off += (size_t)NB * NA * 4;
    int*    n_match = (int*)(w + off);    off += (size_t)NB * NA * 4;
    int*    mg_min  = (int*)(w + off);    off += (size_t)NB * NA * 4;

    dim3 gA(NA / 256, NB);   // 84 x 16 = NBLK

    k_init<<<dim3((NB * NA + 255) / 256), 256, 0, stream>>>(n_match, mg_min, ccount);
    k_decode<<<gA, 256, 0, stream>>>(reg0, obj0, reg1, obj1, reg2, obj2, labels,
                                     A0, A1, cidx, ccount);
    k_assign<<<dim3(NB * NG), 256, 0, stream>>>(labels, A0, A1, cidx, ccount,
                                                n_match, mg_min);
    k_loss<<<gA, 256, 0, stream>>>(labels, obj0, obj1, obj2, A0, A1,
                                   n_match, mg_min, pIl, pObj, pNf);
    k_fin<<<1, 256, 0, stream>>>(pIl, pObj, pNf, labels, out);
}

// Round 5
// 232.925 us; speedup vs baseline: 2.6453x; 1.2979x over previous
//
#include <hip/hip_runtime.h>
#include <math.h>

#define NA   21504   // 128^2 + 64^2 + 32^2
#define NA0  16384
#define NA01 20480
#define NG   100
#define NB   16
#define NC   10      // N_CAND
#define NBLK 1344    // k_loss blocks = 84 * 16
#define MAXC 192     // candidate cap (true max in_both = 75)

__device__ __forceinline__ float softplusf(float x) {
    // jax.nn.softplus == max(x,0) + log1p(exp(-|x|))
    return fmaxf(x, 0.f) + log1pf(expf(-fabsf(x)));
}

// ---------------- decode + fg_anchor + compaction + scratch init ----------------
// A0 = (p_tlx, p_tly, p_brx, p_bry) predicted box corners; OC = softplus(-obj_logit)
__global__ __launch_bounds__(256) void k_decode(
    const float* __restrict__ reg0, const float* __restrict__ obj0,
    const float* __restrict__ reg1, const float* __restrict__ obj1,
    const float* __restrict__ reg2, const float* __restrict__ obj2,
    const float* __restrict__ labels,
    float4* __restrict__ A0, float* __restrict__ OC,
    int* __restrict__ cidx, int* __restrict__ ccount,
    int* __restrict__ n_match, int* __restrict__ mg_min)
{
    int b = blockIdx.y;
    int a = blockIdx.x * 256 + threadIdx.x;   // NA == 84*256; each block is one stride level
    int tid = threadIdx.x;

    int x, y, hw, loc; float s;
    const float* regp; const float* objp;
    if (a < NA0)       { x = a & 127;           y = a >> 7; s = 8.f;  hw = 16384; loc = y * 128 + x; regp = reg0; objp = obj0; }
    else if (a < NA01) { int i = a - NA0;  x = i & 63; y = i >> 6; s = 16.f; hw = 4096;  loc = y * 64 + x;  regp = reg1; objp = obj1; }
    else               { int i = a - NA01; x = i & 31; y = i >> 5; s = 32.f; hw = 1024;  loc = y * 32 + x;  regp = reg2; objp = obj2; }
    float xc = ((float)x + 0.5f) * s;
    float yc = ((float)y + 0.5f) * s;
    float r  = 2.5f * s;   // block-uniform

    // Per-GT precompute in LDS: tlx,tly,brx,bry, gx-r, gx+r, gy-r, gy+r
    __shared__ float lg[NG][8];
    for (int g = tid; g < NG; g += 256) {
        const float* L = labels + (b * NG + g) * 5;
        float gx = L[1], gy = L[2], gw = L[3], gh = L[4];
        lg[g][0] = gx - 0.5f * gw;
        lg[g][1] = gy - 0.5f * gh;
        lg[g][2] = gx + 0.5f * gw;
        lg[g][3] = gy + 0.5f * gh;
        lg[g][4] = gx - r;
        lg[g][5] = gx + r;
        lg[g][6] = gy - r;
        lg[g][7] = gy + r;
    }
    __syncthreads();

    float r0 = regp[(b * 4 + 0) * hw + loc];
    float r1 = regp[(b * 4 + 1) * hw + loc];
    float r2 = regp[(b * 4 + 2) * hw + loc];
    float r3 = regp[(b * 4 + 3) * hw + loc];
    float ol = objp[b * hw + loc];

    float px = (r0 + (float)x) * s, py = (r1 + (float)y) * s;
    float pw = expf(r2) * s,        ph = expf(r3) * s;

    // fg_anchor over all 100 GT rows (including zeroed invalid rows, per reference)
    bool fga = false;
    #pragma unroll 4
    for (int g = 0; g < NG; g++) {
        float bl = xc - lg[g][0], br = lg[g][2] - xc;
        float bt = yc - lg[g][1], bb = lg[g][3] - yc;
        float m1 = fminf(fminf(bl, br), fminf(bt, bb));
        float cl = xc - lg[g][4], cr = lg[g][5] - xc;
        float ct = yc - lg[g][6], cb = lg[g][7] - yc;
        float m2 = fminf(fminf(cl, cr), fminf(ct, cb));
        fga = fga || (fmaxf(m1, m2) > 0.f);
    }

    int idx = b * NA + a;
    A0[idx] = make_float4(px - 0.5f * pw, py - 0.5f * ph, px + 0.5f * pw, py + 0.5f * ph);
    OC[idx] = softplusf(-ol);
    n_match[idx] = 0;
    mg_min[idx]  = 0x7fffffff;

    // wave-ballot compaction of fg anchors into cidx[b]
    unsigned long long mask = __ballot(fga);
    if (fga) {
        int lane = tid & 63;
        int prefix = __popcll(mask & ((1ull << lane) - 1ull));
        int first  = __ffsll(mask) - 1;
        int base = 0;
        if (lane == first) base = atomicAdd(&ccount[b], __popcll(mask));
        base = __shfl(base, first, 64);
        cidx[b * NA + base + prefix] = a;
    }
}

// ---------------- per-(b,g) assignment: iou top-10 scan + analytic candidates ----------------
__global__ __launch_bounds__(256) void k_assign(
    const float* __restrict__ labels, const float4* __restrict__ A0,
    const float* __restrict__ OC, const int* __restrict__ cidx,
    const int* __restrict__ ccount,
    int* __restrict__ n_match, int* __restrict__ mg_min)
{
    int blk = blockIdx.x;
    int b = blk / NG, g = blk % NG;
    const float* L = labels + (b * NG + g) * 5;
    float l0 = L[0], gx = L[1], gy = L[2], gw = L[3], gh = L[4];
    bool gv = (l0 + gx + gy + gw + gh) > 0.f;
    if (!gv) return;                       // whole block exits uniformly
    int tid = threadIdx.x;

    float g_tlx = gx - 0.5f * gw, g_tly = gy - 0.5f * gh;
    float g_brx = gx + 0.5f * gw, g_bry = gy + 0.5f * gh;
    float ag = gw * gh;

    int cnt = ccount[b];
    int bbase = b * NA;

    __shared__ float sio[256 * NC];   // iou merge; reused as fallback cost array
    __shared__ int   si2[256 * NC];   // fallback idx array
    __shared__ int   cand_a[MAXC];
    __shared__ float cand_c[MAXC];
    __shared__ int   scnt;
    if (tid == 0) scnt = 0;

    // ---- pass A: per-thread top-NC iou over compacted fg anchors ----
    float tio[NC];
    #pragma unroll
    for (int k = 0; k < NC; k++) tio[k] = 0.f;

    for (int m = tid; m < cnt; m += 256) {
        int a = cidx[bbase + m];
        float4 c0 = A0[bbase + a];
        float pa = (c0.z - c0.x) * (c0.w - c0.y);
        float tlx = fmaxf(g_tlx, c0.x), tly = fmaxf(g_tly, c0.y);
        float brx = fminf(g_brx, c0.z), bry = fminf(g_bry, c0.w);
        bool en = (tlx < brx) && (tly < bry);
        float ai = en ? (brx - tlx) * (bry - tly) : 0.f;
        float iou = ai / (ag + pa - ai + 1e-16f);
        if (iou > tio[NC - 1]) {
            tio[NC - 1] = iou;
            #pragma unroll
            for (int j = NC - 1; j > 0; --j) {
                if (tio[j] > tio[j - 1]) { float t = tio[j]; tio[j] = tio[j - 1]; tio[j - 1] = t; }
            }
        }
    }

    #pragma unroll
    for (int k = 0; k < NC; k++) sio[tid * NC + k] = tio[k];
    __syncthreads();

    for (int off = 128; off > 0; off >>= 1) {
        if (tid < off) {
            int abase = tid * NC, bb2 = (tid + off) * NC;
            int i = 0, j = 0;
            float oo_[NC];
            #pragma unroll
            for (int k = 0; k < NC; k++) {
                float va = sio[abase + i], vb = sio[bb2 + j];
                bool ta = va >= vb;
                oo_[k] = ta ? va : vb;
                i += ta ? 1 : 0; j += ta ? 0 : 1;
            }
            #pragma unroll
            for (int k = 0; k < NC; k++) sio[abase + k] = oo_[k];
        }
        __syncthreads();
    }

    // dyn_k (uniform: all threads read sio[0..9], descending order sum)
    float s10 = 0.f;
    #pragma unroll
    for (int k = 0; k < NC; k++) s10 += sio[k];
    int dk = (int)s10;                       // trunc, like astype(int32)
    if (dk < 1) dk = 1;
    if (dk > NC) dk = NC;

    // ---- analytic candidate enumeration: in_both anchors (exact reference tests) ----
    for (int lev = 0; lev < 3; lev++) {
        float s  = (lev == 0) ? 8.f : ((lev == 1) ? 16.f : 32.f);
        int   W  = (lev == 0) ? 128 : ((lev == 1) ? 64 : 32);
        int aofs = (lev == 0) ? 0 : ((lev == 1) ? NA0 : NA01);
        float rr = 2.5f * s;
        float gxr_lo = gx - rr, gxr_hi = gx + rr;
        float gyr_lo = gy - rr, gyr_hi = gy + rr;
        float lox = fmaxf(g_tlx, gxr_lo), hix = fminf(g_brx, gxr_hi);
        float loy = fmaxf(g_tly, gyr_lo), hiy = fminf(g_bry, gyr_hi);
        int ixA = (int)floorf(lox / s - 0.5f) - 1;
        int ixB = (int)ceilf (hix / s - 0.5f) + 1;
        int iyA = (int)floorf(loy / s - 0.5f) - 1;
        int iyB = (int)ceilf (hiy / s - 0.5f) + 1;
        ixA = max(ixA, 0); ixB = min(ixB, W - 1);
        iyA = max(iyA, 0); iyB = min(iyB, W - 1);
        int nx = ixB - ixA + 1, ny = iyB - iyA + 1;
        int nt = (nx > 0 && ny > 0) ? nx * ny : 0;
        for (int t = tid; t < nt; t += 256) {
            int ix = ixA + t % nx, iy = iyA + t / nx;
            float xcA = ((float)ix + 0.5f) * s;
            float ycA = ((float)iy + 0.5f) * s;
            // exact reference in_boxes / in_centers tests
            float bl = xcA - g_tlx, brr = g_brx - xcA;
            float bt = ycA - g_tly, bbb = g_bry - ycA;
            bool inb = fminf(fminf(bl, brr), fminf(bt, bbb)) > 0.f;
            float cl = xcA - gxr_lo, cr = gxr_hi - xcA;
            float ct = ycA - gyr_lo, cb = gyr_hi - ycA;
            bool inc = fminf(fminf(cl, cr), fminf(ct, cb)) > 0.f;
            if (inb && inc) {
                int p = atomicAdd(&scnt, 1);
                if (p < MAXC) cand_a[p] = aofs + iy * W + ix;
            }
        }
    }
    __syncthreads();
    int nc_ = min(scnt, MAXC);

    if (dk <= nc_) {
        // ---- common path: cost + stable rank among candidates only ----
        for (int ci = tid; ci < nc_; ci += 256) {
            int a = cand_a[ci];
            float4 c0 = A0[bbase + a];
            float pa = (c0.z - c0.x) * (c0.w - c0.y);
            float tlx = fmaxf(g_tlx, c0.x), tly = fmaxf(g_tly, c0.y);
            float brx = fminf(g_brx, c0.z), bry = fminf(g_bry, c0.w);
            bool en = (tlx < brx) && (tly < bry);
            float ai = en ? (brx - tlx) * (bry - tly) : 0.f;
            float iou = ai / (ag + pa - ai + 1e-16f);
            cand_c[ci] = OC[bbase + a] + 3.0f * (-__logf(iou + 1e-8f));
        }
        __syncthreads();
        for (int ci = tid; ci < nc_; ci += 256) {
            float c = cand_c[ci]; int a = cand_a[ci];
            int rank = 0;
            for (int j = 0; j < nc_; j++) {
                float cj = cand_c[j]; int aj = cand_a[j];
                rank += (cj < c || (cj == c && aj < a)) ? 1 : 0;
            }
            if (rank < dk) {
                atomicAdd(&n_match[bbase + a], 1);
                atomicMin(&mg_min[bbase + a], g);
            }
        }
    } else {
        // ---- rare fallback: full cost scan over compacted list ----
        float fc[NC]; int fa[NC];
        #pragma unroll
        for (int k = 0; k < NC; k++) { fc[k] = 3.4e38f; fa[k] = 0x7fffffff; }
        for (int m = tid; m < cnt; m += 256) {
            int a = cidx[bbase + m];
            float4 c0 = A0[bbase + a];
            float pa = (c0.z - c0.x) * (c0.w - c0.y);
            float tlx = fmaxf(g_tlx, c0.x), tly = fmaxf(g_tly, c0.y);
            float brx = fminf(g_brx, c0.z), bry = fminf(g_bry, c0.w);
            bool en = (tlx < brx) && (tly < bry);
            float ai = en ? (brx - tlx) * (bry - tly) : 0.f;
            float iou = ai / (ag + pa - ai + 1e-16f);
            int lev2; int xx, yy; float s2;
            if (a < NA0)       { xx = a & 127;           yy = a >> 7;  s2 = 8.f;  lev2 = 0; }
            else if (a < NA01) { int i2 = a - NA0;  xx = i2 & 63; yy = i2 >> 6; s2 = 16.f; lev2 = 1; }
            else               { int i2 = a - NA01; xx = i2 & 31; yy = i2 >> 5; s2 = 32.f; lev2 = 2; }
            (void)lev2;
            float xcA = ((float)xx + 0.5f) * s2, ycA = ((float)yy + 0.5f) * s2;
            float rr2 = 2.5f * s2;
            float bl = xcA - g_tlx, brr = g_brx - xcA;
            float bt = ycA - g_tly, bbb = g_bry - ycA;
            bool inb = fminf(fminf(bl, brr), fminf(bt, bbb)) > 0.f;
            float cl = xcA - (gx - rr2), cr = (gx + rr2) - xcA;
            float ct = ycA - (gy - rr2), cb = (gy + rr2) - ycA;
            bool inc = fminf(fminf(cl, cr), fminf(ct, cb)) > 0.f;
            float c = OC[bbase + a] + 3.0f * (-__logf(iou + 1e-8f));
            if (!(inb && inc)) c += 100000.0f;
            if (c < fc[NC - 1] || (c == fc[NC - 1] && a < fa[NC - 1])) {
                fc[NC - 1] = c; fa[NC - 1] = a;
                #pragma unroll
                for (int j = NC - 1; j > 0; --j) {
                    bool sw = (fc[j] < fc[j - 1]) || (fc[j] == fc[j - 1] && fa[j] < fa[j - 1]);
                    if (sw) {
                        float t1 = fc[j]; fc[j] = fc[j - 1]; fc[j - 1] = t1;
                        int   t2 = fa[j]; fa[j] = fa[j - 1]; fa[j - 1] = t2;
                    }
                }
            }
        }
        __syncthreads();   // everyone done with sio (dk already computed)
        #pragma unroll
        for (int k = 0; k < NC; k++) { sio[tid * NC + k] = fc[k]; si2[tid * NC + k] = fa[k]; }
        __syncthreads();
        for (int off = 128; off > 0; off >>= 1) {
            if (tid < off) {
                int abase = tid * NC, bb2 = (tid + off) * NC;
                int i = 0, j = 0;
                float oc_[NC]; int oi_[NC];
                #pragma unroll
                for (int k = 0; k < NC; k++) {
                    float ca = sio[abase + i], cb3 = sio[bb2 + j];
                    int   ia = si2[abase + i], ib  = si2[bb2 + j];
                    bool ta = (ca < cb3) || (ca == cb3 && ia <= ib);
                    oc_[k] = ta ? ca : cb3; oi_[k] = ta ? ia : ib;
                    i += ta ? 1 : 0; j += ta ? 0 : 1;
                }
                #pragma unroll
                for (int k = 0; k < NC; k++) { sio[abase + k] = oc_[k]; si2[abase + k] = oi_[k]; }
            }
            __syncthreads();
        }
        if (tid == 0) {
            for (int k = 0; k < dk; k++) {
                int aa = si2[k];
                if (aa != 0x7fffffff) {
                    atomicAdd(&n_match[bbase + aa], 1);
                    atomicMin(&mg_min[bbase + aa], g);
                }
            }
        }
    }
}

// ---------------- resolution (lazy best_gt) + per-block partial sums ----------------
__global__ __launch_bounds__(256) void k_loss(
    const float* __restrict__ labels,
    const float* __restrict__ obj0, const float* __restrict__ obj1,
    const float* __restrict__ obj2,
    const float4* __restrict__ A0, const float* __restrict__ OC,
    const int* __restrict__ n_match, const int* __restrict__ mg_min,
    float* __restrict__ pIl, float* __restrict__ pObj, int* __restrict__ pNf)
{
    int b = blockIdx.y;
    int a = blockIdx.x * 256 + threadIdx.x;
    int idx = b * NA + a;
    int tid = threadIdx.x;

    __shared__ float lbl[NG * 5];
    for (int i = tid; i < NG * 5; i += 256) lbl[i] = labels[b * NG * 5 + i];
    __syncthreads();

    // reload obj logit from inputs
    int x, y, hw, loc;
    const float* objp;
    float rr, s;
    if (a < NA0)       { x = a & 127;           y = a >> 7; hw = 16384; loc = y * 128 + x; objp = obj0; rr = 20.f; s = 8.f; }
    else if (a < NA01) { int i = a - NA0;  x = i & 63; y = i >> 6; hw = 4096;  loc = y * 64 + x;  objp = obj1; rr = 40.f; s = 16.f; }
    else               { int i = a - NA01; x = i & 31; y = i >> 5; hw = 1024;  loc = y * 32 + x;  objp = obj2; rr = 80.f; s = 32.f; }
    float ol = objp[b * hw + loc];

    int n = n_match[idx];
    bool fg = false; int mg = 0;
    if (n == 1) { fg = true; mg = mg_min[idx]; }
    else if (n > 1) {
        // lazy best_gt = argmin_g cost (rare lanes)
        float4 c0 = A0[idx];
        float pa = (c0.z - c0.x) * (c0.w - c0.y);
        float oc = OC[idx];
        float xcA = ((float)x + 0.5f) * s, ycA = ((float)y + 0.5f) * s;
        float bestc = 3.4e38f; int bg = 0;
        for (int g = 0; g < NG; g++) {
            float l0 = lbl[g * 5 + 0], gx = lbl[g * 5 + 1], gy = lbl[g * 5 + 2];
            float gw = lbl[g * 5 + 3], gh = lbl[g * 5 + 4];
            bool gvv = (l0 + gx + gy + gw + gh) > 0.f;
            float tlx = fmaxf(gx - 0.5f * gw, c0.x), tly = fmaxf(gy - 0.5f * gh, c0.y);
            float brx = fminf(gx + 0.5f * gw, c0.z), bry = fminf(gy + 0.5f * gh, c0.w);
            bool en = (tlx < brx) && (tly < bry);
            float ai = en ? (brx - tlx) * (bry - tly) : 0.f;
            float iou = ai / (gw * gh + pa - ai + 1e-16f);
            float bl = xcA - (gx - 0.5f * gw), br = (gx + 0.5f * gw) - xcA;
            float bt = ycA - (gy - 0.5f * gh), bb = (gy + 0.5f * gh) - ycA;
            bool inb = fminf(fminf(bl, br), fminf(bt, bb)) > 0.f;
            float cl = xcA - (gx - rr), cr = (gx + rr) - xcA;
            float ct = ycA - (gy - rr), cb = (gy + rr) - ycA;
            bool inc = fminf(fminf(cl, cr), fminf(ct, cb)) > 0.f;
            float c = oc + 3.0f * (-__logf(iou + 1e-8f));
            if (!(inb && inc)) c += 100000.0f;
            if (!gvv)          c += 10000000.0f;   // n>1 anchors are always fg_anchor
            if (c < bestc) { bestc = c; bg = g; }
        }
        bool gvv = (lbl[bg * 5 + 0] + lbl[bg * 5 + 1] + lbl[bg * 5 + 2] +
                    lbl[bg * 5 + 3] + lbl[bg * 5 + 4]) > 0.f;
        if (gvv) { fg = true; mg = bg; }
    }

    float objl = softplusf(ol) - (fg ? ol : 0.f);
    float il = 0.f;
    if (fg) {
        float4 c0 = A0[idx];
        float pa = (c0.z - c0.x) * (c0.w - c0.y);
        float gx = lbl[mg * 5 + 1], gy = lbl[mg * 5 + 2];
        float gw = lbl[mg * 5 + 3], gh = lbl[mg * 5 + 4];
        float tlx = fmaxf(c0.x, gx - 0.5f * gw);
        float tly = fmaxf(c0.y, gy - 0.5f * gh);
        float brx = fminf(c0.z, gx + 0.5f * gw);
        float bry = fminf(c0.w, gy + 0.5f * gh);
        bool en = (tlx < brx) && (tly < bry);
        float ai = en ? (brx - tlx) * (bry - tly) : 0.f;
        float iou = ai / (pa + gw * gh - ai + 1e-16f);
        il = 1.f - iou * iou;
    }
    int nf = fg ? 1 : 0;

    // wave reduce, then LDS across the 4 waves, then ONE store per block (no atomics)
    for (int off = 32; off > 0; off >>= 1) {
        objl += __shfl_down(objl, off);
        il   += __shfl_down(il, off);
        nf   += __shfl_down(nf, off);
    }
    __shared__ float wIl[4], wObj[4];
    __shared__ int   wNf[4];
    int wid = tid >> 6;
    if ((tid & 63) == 0) { wIl[wid] = il; wObj[wid] = objl; wNf[wid] = nf; }
    __syncthreads();
    if (tid == 0) {
        float sIl = wIl[0] + wIl[1] + wIl[2] + wIl[3];
        float sObj = wObj[0] + wObj[1] + wObj[2] + wObj[3];
        int   sNf = wNf[0] + wNf[1] + wNf[2] + wNf[3];
        int pb = b * (NA / 256) + blockIdx.x;
        pIl[pb] = sIl; pObj[pb] = sObj; pNf[pb] = sNf;
    }
}

// ---------------- finalize: reduce partials + count gts ----------------
__global__ __launch_bounds__(256) void k_fin(
    const float* __restrict__ pIl, const float* __restrict__ pObj,
    const int* __restrict__ pNf, const float* __restrict__ labels,
    float* __restrict__ out)
{
    int tid = threadIdx.x;
    double dIl = 0.0, dObj = 0.0;
    int nf = 0;
    for (int i = tid; i < NBLK; i += 256) {
        dIl += (double)pIl[i];
        dObj += (double)pObj[i];
        nf += pNf[i];
    }
    int ng = 0;
    for (int i = tid; i < NB * NG; i += 256) {
        const float* L = labels + i * 5;
        if (L[0] + L[1] + L[2] + L[3] + L[4] > 0.f) ng++;
    }
    for (int off = 32; off > 0; off >>= 1) {
        dIl += __shfl_down(dIl, off);
        dObj += __shfl_down(dObj, off);
        nf += __shfl_down(nf, off);
        ng += __shfl_down(ng, off);
    }
    __shared__ double sIl[4], sObj[4];
    __shared__ int sNf[4], sNg[4];
    int wid = tid >> 6;
    if ((tid & 63) == 0) { sIl[wid] = dIl; sObj[wid] = dObj; sNf[wid] = nf; sNg[wid] = ng; }
    __syncthreads();
    if (tid == 0) {
        double tIl = sIl[0] + sIl[1] + sIl[2] + sIl[3];
        double tObj = sObj[0] + sObj[1] + sObj[2] + sObj[3];
        int tNf = sNf[0] + sNf[1] + sNf[2] + sNf[3];
        int tNg = sNg[0] + sNg[1] + sNg[2] + sNg[3];
        float num_fg  = fmaxf((float)tNf, 1.f);
        float num_gts = fmaxf((float)tNg, 1.f);
        float li = (float)(tIl / (double)num_fg);
        float lo = (float)(tObj / (double)num_fg);
        out[0] = 5.f * li + lo;
        out[1] = 5.f * li;
        out[2] = lo;
        out[3] = 0.f;
        out[4] = num_fg / num_gts;
    }
}

extern "C" void kernel_launch(void* const* d_in, const int* in_sizes, int n_in,
                              void* d_out, int out_size, void* d_ws, size_t ws_size,
                              hipStream_t stream)
{
    const float* reg0   = (const float*)d_in[0];
    const float* obj0   = (const float*)d_in[1];
    const float* reg1   = (const float*)d_in[2];
    const float* obj1   = (const float*)d_in[3];
    const float* reg2   = (const float*)d_in[4];
    const float* obj2   = (const float*)d_in[5];
    const float* labels = (const float*)d_in[6];
    float* out = (float*)d_out;

    char* w = (char*)d_ws;
    int*    ccount = (int*)w;             // NB ints
    size_t off = 256;
    float*  pIl  = (float*)(w + off); off += NBLK * 4;
    float*  pObj = (float*)(w + off); off += NBLK * 4;
    int*    pNf  = (int*)(w + off);   off += NBLK * 4;
    off = (off + 255) & ~(size_t)255;
    float4* A0      = (float4*)(w + off); off += (size_t)NB * NA * 16;
    float*  OC      = (float*)(w + off);  off += (size_t)NB * NA * 4;
    int*    cidx    = (int*)(w + off);    off += (size_t)NB * NA * 4;
    int*    n_match = (int*)(w + off);    off += (size_t)NB * NA * 4;
    int*    mg_min  = (int*)(w + off);    off += (size_t)NB * NA * 4;

    dim3 gA(NA / 256, NB);   // 84 x 16 = NBLK

    hipMemsetAsync(ccount, 0, NB * sizeof(int), stream);
    k_decode<<<gA, 256, 0, stream>>>(reg0, obj0, reg1, obj1, reg2, obj2, labels,
                                     A0, OC, cidx, ccount, n_match, mg_min);
    k_assign<<<dim3(NB * NG), 256, 0, stream>>>(labels, A0, OC, cidx, ccount,
                                                n_match, mg_min);
    k_loss<<<gA, 256, 0, stream>>>(labels, obj0, obj1, obj2, A0, OC,
                                   n_match, mg_min, pIl, pObj, pNf);
    k_fin<<<1, 256, 0, stream>>>(pIl, pObj, pNf, labels, out);
}